// Round 8
// baseline (257.293 us; speedup 1.0000x reference)
//
#include <hip/hip_runtime.h>
#include <math.h>

#define DM   1024
#define TTOK 2048
#define NTOK 4096   // B*T

typedef __bf16 bf16x8 __attribute__((ext_vector_type(8)));
typedef __bf16 bf16x4 __attribute__((ext_vector_type(4)));
typedef float  f32x4  __attribute__((ext_vector_type(4)));
typedef float  f32x16 __attribute__((ext_vector_type(16)));

// Q pre-scale: sm_scale (1/8) * log2(e)  -> allows p = exp2(s)
#define QSCALE 0.18033688011112042f

#if defined(__has_builtin)
#if __has_builtin(__builtin_amdgcn_exp2f)
#define EXP2F(x) __builtin_amdgcn_exp2f(x)
#endif
#endif
#ifndef EXP2F
#define EXP2F(x) exp2f(x)
#endif

#define GLDS16(g, l) __builtin_amdgcn_global_load_lds( \
    (__attribute__((address_space(1))) void*)(g),      \
    (__attribute__((address_space(3))) void*)(l), 16, 0, 0)

#define MFMA32(a, b, c) __builtin_amdgcn_mfma_f32_32x32x16_bf16((a), (b), (c), 0, 0, 0)

// ---------------- fp32 -> bf16 convert: x + 4 weights in ONE launch ----------------
__global__ __launch_bounds__(256)
void cvt_all(const float* __restrict__ x,  const float* __restrict__ Wq,
             const float* __restrict__ Wk, const float* __restrict__ Wv,
             const float* __restrict__ Wo, __bf16* __restrict__ dst) {
    size_t g = ((size_t)blockIdx.x * 256 + threadIdx.x) * 8;
    const float* s;
    size_t off;
    const size_t NX = (size_t)NTOK * DM;   // 4M
    if (g < NX) { s = x; off = g; }
    else {
        size_t gg = g - NX;
        int w = (int)(gg >> 20);           // 1M-element segments
        off = gg & ((1u << 20) - 1);
        s = (w == 0) ? Wq : (w == 1) ? Wk : (w == 2) ? Wv : Wo;
    }
    float4 a = *(const float4*)(s + off);
    float4 b = *(const float4*)(s + off + 4);
    bf16x8 v;
    v[0] = (__bf16)a.x; v[1] = (__bf16)a.y; v[2] = (__bf16)a.z; v[3] = (__bf16)a.w;
    v[4] = (__bf16)b.x; v[5] = (__bf16)b.y; v[6] = (__bf16)b.z; v[7] = (__bf16)b.w;
    *(bf16x8*)(dst + g) = v;
}

// =====================================================================
// bf16 MFMA GEMM: C[m,n] = sum_k A[m,k] * B[n,k], 128x128 tile, BK=32.
// MODE 0 (QKV, grid z) with LDS-transpose epilogue (packed 16B stores):
//   z=0: A=Wq, B=x (m=hd, n=token) -> Q[b,h,t,d] * QSCALE
//   z=1: A=Wk, B=x                  -> K[b,h,t,d]
//   z=2: A=x,  B=Wv (m=token, n=hd) -> Vt[b,h,d,t]
// MODE 1 (out-proj): A=Zm (m=token), B=Wo (n=Dout) -> out[t][D] fp32.
// =====================================================================
#define LSTR 136   // LDS transpose stride

template<int MODE>
__global__ __launch_bounds__(256)
void gemm_bf16(const __bf16* __restrict__ X,
               const __bf16* __restrict__ W0, const __bf16* __restrict__ W1,
               const __bf16* __restrict__ W2,
               __bf16* __restrict__ Oq, __bf16* __restrict__ Ok,
               __bf16* __restrict__ Ovt, float* __restrict__ Of)
{
    const int z = (MODE == 0) ? blockIdx.z : 3;
    const __bf16 *A, *B;
    int m0, n0;
    if (MODE == 0 && z < 2) {        // W·x^T : m=hd(1024), n=token(4096)
        A = z ? W1 : W0; B = X;
        m0 = blockIdx.y * 128; n0 = blockIdx.x * 128;
    } else if (MODE == 0) {          // x·Wv^T : m=token, n=hd
        A = X; B = W2;
        m0 = blockIdx.x * 128; n0 = blockIdx.y * 128;
    } else {                         // Zm·Wo^T : m=token(4096), n=Dout(1024)
        A = X; B = W0;
        m0 = blockIdx.y * 128; n0 = blockIdx.x * 128;
    }

    __shared__ __attribute__((aligned(16))) __bf16 smem[128 * LSTR];
    __bf16* As = smem;
    __bf16* Bs = smem + 128 * 32;

    const int tid  = threadIdx.x;
    const int lane = tid & 63;
    const int wave = tid >> 6;
    const int wm = wave & 1, wn = wave >> 1;
    const int col = lane & 15, quad = lane >> 4;

    const __bf16* Ag = A + (size_t)(m0 + (tid >> 2)) * DM + (tid & 3) * 8;
    const __bf16* Bg = B + (size_t)(n0 + (tid >> 2)) * DM + (tid & 3) * 8;
    __bf16* lA = As + tid * 8;
    __bf16* lB = Bs + tid * 8;

    f32x4 acc[4][4];
#pragma unroll
    for (int i = 0; i < 4; ++i)
#pragma unroll
        for (int j = 0; j < 4; ++j)
#pragma unroll
            for (int r = 0; r < 4; ++r) acc[i][j][r] = 0.0f;

    for (int k0 = 0; k0 < DM; k0 += 32) {
        __syncthreads();
        GLDS16(Ag + k0,                   lA);
        GLDS16(Ag + (size_t)64 * DM + k0, lA + 2048);
        GLDS16(Bg + k0,                   lB);
        GLDS16(Bg + (size_t)64 * DM + k0, lB + 2048);
        __syncthreads();
        bf16x8 af[4], bfr[4];
#pragma unroll
        for (int i = 0; i < 4; ++i)
            af[i] = *(const bf16x8*)&As[(wm * 64 + i * 16 + col) * 32 + quad * 8];
#pragma unroll
        for (int j = 0; j < 4; ++j)
            bfr[j] = *(const bf16x8*)&Bs[(wn * 64 + j * 16 + col) * 32 + quad * 8];
#pragma unroll
        for (int i = 0; i < 4; ++i)
#pragma unroll
            for (int j = 0; j < 4; ++j)
                acc[i][j] = __builtin_amdgcn_mfma_f32_16x16x32_bf16(af[i], bfr[j], acc[i][j], 0, 0, 0);
    }

    if (MODE == 1) {
#pragma unroll
        for (int i = 0; i < 4; ++i)
#pragma unroll
            for (int j = 0; j < 4; ++j) {
                const int mb = m0 + wm * 64 + i * 16 + quad * 4;
                const int n  = n0 + wn * 64 + j * 16 + col;
#pragma unroll
                for (int r = 0; r < 4; ++r)
                    Of[(size_t)(mb + r) * DM + n] = acc[i][j][r];
            }
        return;
    }

    // ---- MODE 0: LDS transpose -> packed global stores ----
    const float sc = (z == 0) ? QSCALE : 1.0f;
    __syncthreads();
#pragma unroll
    for (int i = 0; i < 4; ++i)
#pragma unroll
        for (int j = 0; j < 4; ++j) {
            const int ml = wm * 64 + i * 16 + quad * 4;
            const int nl = wn * 64 + j * 16 + col;
            bf16x4 pk;
#pragma unroll
            for (int r = 0; r < 4; ++r) pk[r] = (__bf16)(acc[i][j][r] * sc);
            *(bf16x4*)&smem[nl * LSTR + ml] = pk;   // Ls[n][m]
        }
    __syncthreads();

#pragma unroll
    for (int it = 0; it < 8; ++it) {
        int c   = tid + 256 * it;
        int row = c >> 4;          // n_local
        int ch  = (c & 15) * 8;    // m_local base
        bf16x8 v = *(const bf16x8*)&smem[row * LSTR + ch];
        if (z < 2) {
            int t  = n0 + row;
            int b  = t >> 11; t &= 2047;
            int hd = m0 + ch;
            int h  = hd >> 6, d = hd & 63;
            *(bf16x8*)&((z ? Ok : Oq)[(((size_t)(b * 16 + h)) * TTOK + t) * 64 + d]) = v;
        } else {
            int hd = n0 + row;
            int h  = hd >> 6, d = hd & 63;
            int t  = m0 + ch;
            int b  = t >> 11; t &= 2047;
            *(bf16x8*)&Ovt[(((size_t)(b * 16 + h)) * 64 + d) * TTOK + t] = v;
        }
    }
}

// =====================================================================
// MFMA flash attention v6: wave-autonomous, zero-LDS K-loop.
// 256 thr (4 waves), 64 q/block, 32 q/wave, 2-way split-K (16 tiles/wave).
// K A-frags loaded with sigma-permuted rows (swap bits 2<->3 of c32) so
// S^T's C-layout IS the PV B-operand layout: pf[st] = bf16(s[8st..8st+8)).
// No barriers / no LDS in the loop; K/Vt shared via L1/L2.
// l on VALU (own 32 adds + shfl_xor 32). One LDS combine of (O,l) at end.
// =====================================================================
__global__ __launch_bounds__(256)
void attn_mfma(const __bf16* __restrict__ Qg, const __bf16* __restrict__ Kg,
               const __bf16* __restrict__ Vtg, __bf16* __restrict__ Zm)
{
    const int bh = blockIdx.y;
    const int q0 = blockIdx.x * 64;
    const size_t base = (size_t)bh * TTOK * 64;

    __shared__ float cbuf[2 * 33 * 64];   // [qg][33 regs][lane]

    const int tid  = threadIdx.x;
    const int lane = tid & 63, wave = tid >> 6;
    const int c32  = lane & 31, h32 = lane >> 5;
    const int qg   = wave & 1,  kh  = wave >> 1;
    const int sigc = (c32 & 19) | ((c32 & 4) << 1) | ((c32 & 8) >> 1);  // swap bits 2,3
    const int q    = q0 + qg * 32 + c32;
    const int doff = h32 * 8;

    // ---- Q B-frags (pre-scaled by QSCALE in GEMM) ----
    bf16x8 qf[4];
    {
        const __bf16* qp = Qg + base + (size_t)q * 64 + doff;
#pragma unroll
        for (int st = 0; st < 4; ++st) qf[st] = *(const bf16x8*)(qp + st * 16);
    }

    f32x16 O0, O1;
#pragma unroll
    for (int r = 0; r < 16; ++r) { O0[r] = 0.0f; O1[r] = 0.0f; }
    float lsum = 0.0f;

    const int kb0 = kh * 16, kb1 = kb0 + 16;
    const __bf16* kbase  = Kg  + base + (size_t)sigc * 64 + doff;
    const __bf16* vbase0 = Vtg + base + (size_t)c32 * TTOK + doff;
    const __bf16* vbase1 = Vtg + base + (size_t)(c32 + 32) * TTOK + doff;

    // preload K frags for first tile
    bf16x8 kf0[4], kf1[4];
    {
        const __bf16* kp = kbase + (size_t)kb0 * 4096;
#pragma unroll
        for (int st = 0; st < 4; ++st) {
            kf0[st] = *(const bf16x8*)(kp + st * 16);
            kf1[st] = *(const bf16x8*)(kp + 2048 + st * 16);
        }
    }

    for (int kb = kb0; kb < kb1; ++kb) {
        // ---- S^T = K(sigma-rows) · Q^T ----
        f32x16 s0, s1;
#pragma unroll
        for (int r = 0; r < 16; ++r) { s0[r] = 0.0f; s1[r] = 0.0f; }
#pragma unroll
        for (int st = 0; st < 4; ++st) {
            s0 = MFMA32(kf0[st], qf[st], s0);
            s1 = MFMA32(kf1[st], qf[st], s1);
        }

        // ---- issue current V frag loads (latency covered by exp below) ----
        bf16x8 vf0[4], vf1[4];
        {
            const __bf16* vp0 = vbase0 + kb * 64;
            const __bf16* vp1 = vbase1 + kb * 64;
#pragma unroll
            for (int st = 0; st < 4; ++st) {
                vf0[st] = *(const bf16x8*)(vp0 + st * 16);
                vf1[st] = *(const bf16x8*)(vp1 + st * 16);
            }
        }

        // ---- p = exp2(s); pf[st] = packed s-regs [8st..8st+8) ; l on VALU ----
        bf16x8 pf[4];
        float acc = 0.0f;
#pragma unroll
        for (int st = 0; st < 4; ++st) {
            int b0 = (st & 1) * 8;
#pragma unroll
            for (int j = 0; j < 8; ++j) {
                float p = EXP2F((st < 2) ? s0[b0 + j] : s1[b0 + j]);
                acc += p;
                pf[st][j] = (__bf16)p;
            }
        }
        lsum += acc;

        // ---- O^T += V^T · P ----
#pragma unroll
        for (int st = 0; st < 4; ++st) {
            O0 = MFMA32(vf0[st], pf[st], O0);
            O1 = MFMA32(vf1[st], pf[st], O1);
        }

        // ---- prefetch next K tile (covers until next S-phase) ----
        if (kb + 1 < kb1) {
            const __bf16* kp = kbase + (size_t)(kb + 1) * 4096;
#pragma unroll
            for (int st = 0; st < 4; ++st) {
                kf0[st] = *(const bf16x8*)(kp + st * 16);
                kf1[st] = *(const bf16x8*)(kp + 2048 + st * 16);
            }
        }
    }

    // cross-half key sum for l (partner lane covers complementary 32 keys)
    lsum += __shfl_xor(lsum, 32, 64);

    // ---- combine the two key-halves through LDS ----
    float* cb = cbuf + qg * 33 * 64;
    if (kh == 1) {
#pragma unroll
        for (int r = 0; r < 16; ++r) {
            cb[r * 64 + lane]        = O0[r];
            cb[(16 + r) * 64 + lane] = O1[r];
        }
        cb[32 * 64 + lane] = lsum;
    }
    __syncthreads();
    if (kh == 1) return;
#pragma unroll
    for (int r = 0; r < 16; ++r) {
        O0[r] += cb[r * 64 + lane];
        O1[r] += cb[(16 + r) * 64 + lane];
    }
    lsum += cb[32 * 64 + lane];

    const float inv = 1.0f / lsum;

    // ---- epilogue: Y = O/l ; exclusive output mod ; packed bf16 store ----
    const int b = bh >> 4, h = bh & 15;
    float vq[2][16], y[2][16];
#pragma unroll
    for (int db = 0; db < 2; ++db)
#pragma unroll
        for (int rg = 0; rg < 16; ++rg) {
            int d = db * 32 + (rg & 3) + 8 * (rg >> 2) + 4 * h32;
            vq[db][rg] = (float)Vtg[base + (size_t)d * TTOK + q];
        }
    float yv = 0.f, v2 = 0.f, yy = 0.f;
#pragma unroll
    for (int db = 0; db < 2; ++db)
#pragma unroll
        for (int rg = 0; rg < 16; ++rg) {
            float yval = (db ? O1[rg] : O0[rg]) * inv;
            y[db][rg] = yval;
            yv += yval * vq[db][rg];
            v2 += vq[db][rg] * vq[db][rg];
            yy += yval * yval;
        }
    yv += __shfl_xor(yv, 32, 64);
    v2 += __shfl_xor(v2, 32, 64);
    yy += __shfl_xor(yy, 32, 64);
    float scl = (v2 > 0.0f) ? yv / fmaxf(v2, 1.1754943508222875e-38f) : 0.0f;
    float zz = 0.f;
    float zvv[2][16];
#pragma unroll
    for (int db = 0; db < 2; ++db)
#pragma unroll
        for (int rg = 0; rg < 16; ++rg) {
            zvv[db][rg] = y[db][rg] - scl * vq[db][rg];
            zz += zvv[db][rg] * zvv[db][rg];
        }
    zz += __shfl_xor(zz, 32, 64);
    float znorm = sqrtf(zz);
    float refn  = fmaxf(sqrtf(yy), sqrtf(v2));
    bool  wipe  = (v2 > 0.0f) && (znorm <= 1.1920928955078125e-07f * 64.0f * refn);
#pragma unroll
    for (int db = 0; db < 2; ++db)
#pragma unroll
        for (int g = 0; g < 4; ++g) {
            bf16x4 pk;
#pragma unroll
            for (int r = 0; r < 4; ++r)
                pk[r] = (__bf16)(wipe ? 0.0f : zvv[db][4 * g + r]);
            int d = db * 32 + 8 * g + 4 * h32;
            *(bf16x4*)&Zm[((size_t)(b * TTOK + q)) * DM + h * 64 + d] = pk;
        }
}

// =====================================================================
extern "C" void kernel_launch(void* const* d_in, const int* in_sizes, int n_in,
                              void* d_out, int out_size, void* d_ws, size_t ws_size,
                              hipStream_t stream) {
    const float* x  = (const float*)d_in[0];
    const float* Wq = (const float*)d_in[1];
    const float* Wk = (const float*)d_in[2];
    const float* Wv = (const float*)d_in[3];
    const float* Wo = (const float*)d_in[4];

    const size_t NX = (size_t)NTOK * DM;   // 4M
    const size_t NW = (size_t)DM * DM;     // 1M
    __bf16* xb  = (__bf16*)d_ws;
    __bf16* wqb = xb  + NX;
    __bf16* wkb = wqb + NW;
    __bf16* wvb = wkb + NW;
    __bf16* wob = wvb + NW;
    __bf16* Qb  = wob + NW;
    __bf16* Kb  = Qb  + NX;
    __bf16* Vtb = Kb  + NX;
    __bf16* Zmb = Vtb + NX;   // total 24M bf16 = 48 MB

    cvt_all<<<(NX + 4 * NW) / 2048, 256, 0, stream>>>(x, Wq, Wk, Wv, Wo, xb);

    // QKV: z0/z1 = Wq,Wk · x^T ; z2 = x · Wv^T  (LDS-transpose epilogues)
    gemm_bf16<0><<<dim3(32, 8, 3), 256, 0, stream>>>(
        xb, wqb, wkb, wvb, Qb, Kb, Vtb, nullptr);

    // wave-autonomous attention: 64 q/block, split-K x2
    attn_mfma<<<dim3(TTOK / 64, 32), 256, 0, stream>>>(Qb, Kb, Vtb, Zmb);

    // out = Zm · Wo^T (m=token, n=Dout; scalar n-fastest stores)
    gemm_bf16<1><<<dim3(8, 32), 256, 0, stream>>>(
        Zmb, wob, nullptr, nullptr, nullptr, nullptr, nullptr, (float*)d_out);
}

// Round 9
// 196.648 us; speedup vs baseline: 1.3084x; 1.3084x over previous
//
#include <hip/hip_runtime.h>
#include <math.h>

#define DM   1024
#define TTOK 2048
#define NTOK 4096   // B*T

typedef __bf16 bf16x8 __attribute__((ext_vector_type(8)));
typedef __bf16 bf16x4 __attribute__((ext_vector_type(4)));
typedef float  f32x4  __attribute__((ext_vector_type(4)));
typedef float  f32x16 __attribute__((ext_vector_type(16)));

// Q pre-scale: sm_scale (1/8) * log2(e)  -> allows p = exp2(s)
#define QSCALE 0.18033688011112042f

#if defined(__has_builtin)
#if __has_builtin(__builtin_amdgcn_exp2f)
#define EXP2F(x) __builtin_amdgcn_exp2f(x)
#endif
#endif
#ifndef EXP2F
#define EXP2F(x) exp2f(x)
#endif

#define GLDS16(g, l) __builtin_amdgcn_global_load_lds( \
    (__attribute__((address_space(1))) void*)(g),      \
    (__attribute__((address_space(3))) void*)(l), 16, 0, 0)

#define MFMA32(a, b, c) __builtin_amdgcn_mfma_f32_32x32x16_bf16((a), (b), (c), 0, 0, 0)

// ---------------- fp32 -> bf16 convert: x + 4 weights in ONE launch ----------------
__global__ __launch_bounds__(256)
void cvt_all(const float* __restrict__ x,  const float* __restrict__ Wq,
             const float* __restrict__ Wk, const float* __restrict__ Wv,
             const float* __restrict__ Wo, __bf16* __restrict__ dst) {
    size_t g = ((size_t)blockIdx.x * 256 + threadIdx.x) * 8;
    const float* s;
    size_t off;
    const size_t NX = (size_t)NTOK * DM;   // 4M
    if (g < NX) { s = x; off = g; }
    else {
        size_t gg = g - NX;
        int w = (int)(gg >> 20);           // 1M-element segments
        off = gg & ((1u << 20) - 1);
        s = (w == 0) ? Wq : (w == 1) ? Wk : (w == 2) ? Wv : Wo;
    }
    float4 a = *(const float4*)(s + off);
    float4 b = *(const float4*)(s + off + 4);
    bf16x8 v;
    v[0] = (__bf16)a.x; v[1] = (__bf16)a.y; v[2] = (__bf16)a.z; v[3] = (__bf16)a.w;
    v[4] = (__bf16)b.x; v[5] = (__bf16)b.y; v[6] = (__bf16)b.z; v[7] = (__bf16)b.w;
    *(bf16x8*)(dst + g) = v;
}

// =====================================================================
// bf16 MFMA GEMM: C[m,n] = sum_k A[m,k] * B[n,k], 128x128 tile, BK=32.
// MODE 0 (QKV, grid z) with LDS-transpose epilogue (packed 16B stores):
//   z=0: A=Wq, B=x (m=hd, n=token) -> Q[b,h,t,d] * QSCALE
//   z=1: A=Wk, B=x                  -> K[b,h,t,d]
//   z=2: A=x,  B=Wv (m=token, n=hd) -> Vt[b,h,d,t]
// MODE 1 (out-proj): A=Zm (m=token), B=Wo (n=Dout) -> out[t][D] fp32.
// =====================================================================
#define LSTR 136   // LDS transpose stride

template<int MODE>
__global__ __launch_bounds__(256)
void gemm_bf16(const __bf16* __restrict__ X,
               const __bf16* __restrict__ W0, const __bf16* __restrict__ W1,
               const __bf16* __restrict__ W2,
               __bf16* __restrict__ Oq, __bf16* __restrict__ Ok,
               __bf16* __restrict__ Ovt, float* __restrict__ Of)
{
    const int z = (MODE == 0) ? blockIdx.z : 3;
    const __bf16 *A, *B;
    int m0, n0;
    if (MODE == 0 && z < 2) {        // W·x^T : m=hd(1024), n=token(4096)
        A = z ? W1 : W0; B = X;
        m0 = blockIdx.y * 128; n0 = blockIdx.x * 128;
    } else if (MODE == 0) {          // x·Wv^T : m=token, n=hd
        A = X; B = W2;
        m0 = blockIdx.x * 128; n0 = blockIdx.y * 128;
    } else {                         // Zm·Wo^T : m=token(4096), n=Dout(1024)
        A = X; B = W0;
        m0 = blockIdx.y * 128; n0 = blockIdx.x * 128;
    }

    __shared__ __attribute__((aligned(16))) __bf16 smem[128 * LSTR];
    __bf16* As = smem;
    __bf16* Bs = smem + 128 * 32;

    const int tid  = threadIdx.x;
    const int lane = tid & 63;
    const int wave = tid >> 6;
    const int wm = wave & 1, wn = wave >> 1;
    const int col = lane & 15, quad = lane >> 4;

    const __bf16* Ag = A + (size_t)(m0 + (tid >> 2)) * DM + (tid & 3) * 8;
    const __bf16* Bg = B + (size_t)(n0 + (tid >> 2)) * DM + (tid & 3) * 8;
    __bf16* lA = As + tid * 8;
    __bf16* lB = Bs + tid * 8;

    f32x4 acc[4][4];
#pragma unroll
    for (int i = 0; i < 4; ++i)
#pragma unroll
        for (int j = 0; j < 4; ++j)
#pragma unroll
            for (int r = 0; r < 4; ++r) acc[i][j][r] = 0.0f;

    for (int k0 = 0; k0 < DM; k0 += 32) {
        __syncthreads();
        GLDS16(Ag + k0,                   lA);
        GLDS16(Ag + (size_t)64 * DM + k0, lA + 2048);
        GLDS16(Bg + k0,                   lB);
        GLDS16(Bg + (size_t)64 * DM + k0, lB + 2048);
        __syncthreads();
        bf16x8 af[4], bfr[4];
#pragma unroll
        for (int i = 0; i < 4; ++i)
            af[i] = *(const bf16x8*)&As[(wm * 64 + i * 16 + col) * 32 + quad * 8];
#pragma unroll
        for (int j = 0; j < 4; ++j)
            bfr[j] = *(const bf16x8*)&Bs[(wn * 64 + j * 16 + col) * 32 + quad * 8];
#pragma unroll
        for (int i = 0; i < 4; ++i)
#pragma unroll
            for (int j = 0; j < 4; ++j)
                acc[i][j] = __builtin_amdgcn_mfma_f32_16x16x32_bf16(af[i], bfr[j], acc[i][j], 0, 0, 0);
    }

    if (MODE == 1) {
#pragma unroll
        for (int i = 0; i < 4; ++i)
#pragma unroll
            for (int j = 0; j < 4; ++j) {
                const int mb = m0 + wm * 64 + i * 16 + quad * 4;
                const int n  = n0 + wn * 64 + j * 16 + col;
#pragma unroll
                for (int r = 0; r < 4; ++r)
                    Of[(size_t)(mb + r) * DM + n] = acc[i][j][r];
            }
        return;
    }

    // ---- MODE 0: LDS transpose -> packed global stores ----
    const float sc = (z == 0) ? QSCALE : 1.0f;
    __syncthreads();
#pragma unroll
    for (int i = 0; i < 4; ++i)
#pragma unroll
        for (int j = 0; j < 4; ++j) {
            const int ml = wm * 64 + i * 16 + quad * 4;
            const int nl = wn * 64 + j * 16 + col;
            bf16x4 pk;
#pragma unroll
            for (int r = 0; r < 4; ++r) pk[r] = (__bf16)(acc[i][j][r] * sc);
            *(bf16x4*)&smem[nl * LSTR + ml] = pk;   // Ls[n][m]
        }
    __syncthreads();

#pragma unroll
    for (int it = 0; it < 8; ++it) {
        int c   = tid + 256 * it;
        int row = c >> 4;          // n_local
        int ch  = (c & 15) * 8;    // m_local base
        bf16x8 v = *(const bf16x8*)&smem[row * LSTR + ch];
        if (z < 2) {
            int t  = n0 + row;
            int b  = t >> 11; t &= 2047;
            int hd = m0 + ch;
            int h  = hd >> 6, d = hd & 63;
            *(bf16x8*)&((z ? Ok : Oq)[(((size_t)(b * 16 + h)) * TTOK + t) * 64 + d]) = v;
        } else {
            int hd = n0 + row;
            int h  = hd >> 6, d = hd & 63;
            int t  = m0 + ch;
            int b  = t >> 11; t &= 2047;
            *(bf16x8*)&Ovt[(((size_t)(b * 16 + h)) * 64 + d) * TTOK + t] = v;
        }
    }
}

// =====================================================================
// MFMA flash attention v7: LDS-staged, sigma-permuted K (P stays in regs),
// 8 waves (512 thr), 128 q/block, 2-way split-K. wave = (qg 0..3, kh 0..1).
// S^T = K(sigma-rows)·Q^T; pf built directly from s-regs (v6-verified map);
// O^T = V^T·P; l on VALU; fp32 (O,l) combine through LDS at end.
// LDS 55.3 KB: Ks0/Ks1/Vs0/Vs1 (4x 64x72) + QPs (128x72 Q stage).
// =====================================================================
__global__ __launch_bounds__(512, 4)
void attn_mfma(const __bf16* __restrict__ Qg, const __bf16* __restrict__ Kg,
               const __bf16* __restrict__ Vtg, __bf16* __restrict__ Zm)
{
    const int bh = blockIdx.y;
    const int q0 = blockIdx.x * 128;
    const size_t base = (size_t)bh * TTOK * 64;

    __shared__ __attribute__((aligned(16))) __bf16 smem[4 * 64 * 72 + 128 * 72];
    __bf16* Ks0 = smem;
    __bf16* Ks1 = smem + 4608;
    __bf16* Vs0 = smem + 9216;
    __bf16* Vs1 = smem + 13824;
    __bf16* QPs = smem + 18432;   // 128 x 72 Q staging

    const int tid  = threadIdx.x;
    const int lane = tid & 63, wave = tid >> 6;   // 8 waves
    const int c32  = lane & 31, h32 = lane >> 5;
    const int qg   = wave & 3,  kh  = wave >> 2;
    const int sigc = (c32 & 19) | ((c32 & 4) << 1) | ((c32 & 8) >> 1);  // swap bits 2,3

    // ---- stage Q (pre-scaled by QSCALE in GEMM): 128 rows x 64 ----
    {
        int r = tid >> 2, off = (tid & 3) * 16;
        const __bf16* src = Qg + base + (size_t)(q0 + r) * 64 + off;
        *(bf16x8*)&QPs[r * 72 + off]     = *(const bf16x8*)(src);
        *(bf16x8*)&QPs[r * 72 + off + 8] = *(const bf16x8*)(src + 8);
    }
    __syncthreads();
    bf16x8 qf[4];
#pragma unroll
    for (int st = 0; st < 4; ++st)
        qf[st] = *(const bf16x8*)&QPs[(qg * 32 + c32) * 72 + h32 * 8 + st * 16];

    const __bf16* Ksel = kh ? Ks1 : Ks0;
    const __bf16* Vsel = kh ? Vs1 : Vs0;

    f32x16 O0, O1;
#pragma unroll
    for (int r = 0; r < 16; ++r) { O0[r] = 0.0f; O1[r] = 0.0f; }
    float lsum = 0.0f;

    // ---- staging pointers: 512 thr cover 4 x (64 rows x 64) per tile ----
    const int rs = tid >> 3, offs = (tid & 7) * 8;
    const __bf16* gK0 = Kg  + base + (size_t)rs * 64 + offs;           // + kb*4096
    const __bf16* gK1 = Kg  + base + (size_t)(1024 + rs) * 64 + offs;  // + kb*4096
    const __bf16* gV0 = Vtg + base + (size_t)rs * TTOK + offs;         // + kb*64
    const __bf16* gV1 = gV0 + 1024;

    // prefetch tile 0
    bf16x8 kr0 = *(const bf16x8*)(gK0);
    bf16x8 kr1 = *(const bf16x8*)(gK1);
    bf16x8 vr0 = *(const bf16x8*)(gV0);
    bf16x8 vr1 = *(const bf16x8*)(gV1);

    for (int kb = 0; kb < 16; ++kb) {
        __syncthreads();   // prior tile's frag reads complete
        *(bf16x8*)&Ks0[rs * 72 + offs] = kr0;
        *(bf16x8*)&Ks1[rs * 72 + offs] = kr1;
        *(bf16x8*)&Vs0[rs * 72 + offs] = vr0;
        *(bf16x8*)&Vs1[rs * 72 + offs] = vr1;
        __syncthreads();

        // prefetch next tile — latency spans the compute below
        if (kb + 1 < 16) {
            kr0 = *(const bf16x8*)(gK0 + (kb + 1) * 4096);
            kr1 = *(const bf16x8*)(gK1 + (kb + 1) * 4096);
            vr0 = *(const bf16x8*)(gV0 + (kb + 1) * 64);
            vr1 = *(const bf16x8*)(gV1 + (kb + 1) * 64);
        }

        // ---- S^T = K(sigma-rows) · Q^T ----
        f32x16 s0, s1;
#pragma unroll
        for (int r = 0; r < 16; ++r) { s0[r] = 0.0f; s1[r] = 0.0f; }
#pragma unroll
        for (int st = 0; st < 4; ++st) {
            bf16x8 a0 = *(const bf16x8*)&Ksel[(sigc)      * 72 + h32 * 8 + st * 16];
            bf16x8 a1 = *(const bf16x8*)&Ksel[(32 + sigc) * 72 + h32 * 8 + st * 16];
            s0 = MFMA32(a0, qf[st], s0);
            s1 = MFMA32(a1, qf[st], s1);
        }

        // ---- p = exp2(s); pf[st] = packed s-regs (v6-verified layout) ----
        bf16x8 pf[4];
        float acc = 0.0f;
#pragma unroll
        for (int st = 0; st < 4; ++st) {
            int b0 = (st & 1) * 8;
#pragma unroll
            for (int j = 0; j < 8; ++j) {
                float p = EXP2F((st < 2) ? s0[b0 + j] : s1[b0 + j]);
                acc += p;
                pf[st][j] = (__bf16)p;
            }
        }
        lsum += acc;

        // ---- O^T += V^T · P ----
#pragma unroll
        for (int st = 0; st < 4; ++st) {
            bf16x8 v0 = *(const bf16x8*)&Vsel[(c32)      * 72 + h32 * 8 + st * 16];
            bf16x8 v1 = *(const bf16x8*)&Vsel[(32 + c32) * 72 + h32 * 8 + st * 16];
            O0 = MFMA32(v0, pf[st], O0);
            O1 = MFMA32(v1, pf[st], O1);
        }
    }

    // per-q l: partner h32 lane holds the complementary keys
    lsum += __shfl_xor(lsum, 32, 64);

    // ---- combine the two key-halves through LDS (reuse Ks/Vs region) ----
    float* cO = (float*)smem;            // [4 qg][32 regs][64 lanes]
    float* cL = cO + 4 * 32 * 64;        // [4 qg][64 lanes]
    __syncthreads();
    if (kh == 1) {
        float* cw = cO + qg * 2048;
#pragma unroll
        for (int r = 0; r < 16; ++r) {
            cw[r * 64 + lane]        = O0[r];
            cw[(16 + r) * 64 + lane] = O1[r];
        }
        cL[qg * 64 + lane] = lsum;
    }
    __syncthreads();
    if (kh == 1) return;
    {
        float* cw = cO + qg * 2048;
#pragma unroll
        for (int r = 0; r < 16; ++r) {
            O0[r] += cw[r * 64 + lane];
            O1[r] += cw[(16 + r) * 64 + lane];
        }
        lsum += cL[qg * 64 + lane];
    }

    const float inv = 1.0f / lsum;
    const int q = q0 + qg * 32 + c32;

    // ---- epilogue: Y = O/l ; exclusive output mod ; packed bf16 store ----
    const int b = bh >> 4, h = bh & 15;
    float vq[2][16], y[2][16];
#pragma unroll
    for (int db = 0; db < 2; ++db)
#pragma unroll
        for (int rg = 0; rg < 16; ++rg) {
            int d = db * 32 + (rg & 3) + 8 * (rg >> 2) + 4 * h32;
            vq[db][rg] = (float)Vtg[base + (size_t)d * TTOK + q];
        }
    float yv = 0.f, v2 = 0.f, yy = 0.f;
#pragma unroll
    for (int db = 0; db < 2; ++db)
#pragma unroll
        for (int rg = 0; rg < 16; ++rg) {
            float yval = (db ? O1[rg] : O0[rg]) * inv;
            y[db][rg] = yval;
            yv += yval * vq[db][rg];
            v2 += vq[db][rg] * vq[db][rg];
            yy += yval * yval;
        }
    yv += __shfl_xor(yv, 32, 64);
    v2 += __shfl_xor(v2, 32, 64);
    yy += __shfl_xor(yy, 32, 64);
    float scl = (v2 > 0.0f) ? yv / fmaxf(v2, 1.1754943508222875e-38f) : 0.0f;
    float zz = 0.f;
    float zvv[2][16];
#pragma unroll
    for (int db = 0; db < 2; ++db)
#pragma unroll
        for (int rg = 0; rg < 16; ++rg) {
            zvv[db][rg] = y[db][rg] - scl * vq[db][rg];
            zz += zvv[db][rg] * zvv[db][rg];
        }
    zz += __shfl_xor(zz, 32, 64);
    float znorm = sqrtf(zz);
    float refn  = fmaxf(sqrtf(yy), sqrtf(v2));
    bool  wipe  = (v2 > 0.0f) && (znorm <= 1.1920928955078125e-07f * 64.0f * refn);
#pragma unroll
    for (int db = 0; db < 2; ++db)
#pragma unroll
        for (int g = 0; g < 4; ++g) {
            bf16x4 pk;
#pragma unroll
            for (int r = 0; r < 4; ++r)
                pk[r] = (__bf16)(wipe ? 0.0f : zvv[db][4 * g + r]);
            int d = db * 32 + 8 * g + 4 * h32;
            *(bf16x4*)&Zm[((size_t)(b * TTOK + q)) * DM + h * 64 + d] = pk;
        }
}

// =====================================================================
extern "C" void kernel_launch(void* const* d_in, const int* in_sizes, int n_in,
                              void* d_out, int out_size, void* d_ws, size_t ws_size,
                              hipStream_t stream) {
    const float* x  = (const float*)d_in[0];
    const float* Wq = (const float*)d_in[1];
    const float* Wk = (const float*)d_in[2];
    const float* Wv = (const float*)d_in[3];
    const float* Wo = (const float*)d_in[4];

    const size_t NX = (size_t)NTOK * DM;   // 4M
    const size_t NW = (size_t)DM * DM;     // 1M
    __bf16* xb  = (__bf16*)d_ws;
    __bf16* wqb = xb  + NX;
    __bf16* wkb = wqb + NW;
    __bf16* wvb = wkb + NW;
    __bf16* wob = wvb + NW;
    __bf16* Qb  = wob + NW;
    __bf16* Kb  = Qb  + NX;
    __bf16* Vtb = Kb  + NX;
    __bf16* Zmb = Vtb + NX;   // total 24M bf16 = 48 MB

    cvt_all<<<(NX + 4 * NW) / 2048, 256, 0, stream>>>(x, Wq, Wk, Wv, Wo, xb);

    // QKV: z0/z1 = Wq,Wk · x^T ; z2 = x · Wv^T  (LDS-transpose epilogues)
    gemm_bf16<0><<<dim3(32, 8, 3), 256, 0, stream>>>(
        xb, wqb, wkb, wvb, Qb, Kb, Vtb, nullptr);

    // v7 attention: 128 q/block, 8 waves, split-K x2
    attn_mfma<<<dim3(TTOK / 128, 32), 512, 0, stream>>>(Qb, Kb, Vtb, Zmb);

    // out = Zm · Wo^T (m=token, n=Dout; scalar n-fastest stores)
    gemm_bf16<1><<<dim3(8, 32), 256, 0, stream>>>(
        Zmb, wob, nullptr, nullptr, nullptr, nullptr, nullptr, (float*)d_out);
}